// Round 1
// 238.610 us; speedup vs baseline: 1.1011x; 1.1011x over previous
//
#include <hip/hip_runtime.h>
#include <hip/hip_bf16.h>

#define N_NODES 20000
#define N_EDGES 320000
#define BATCH 2
#define IN_DIM 32
#define HID 64
#define HEADS 4
#define OUT_DIM 8
#define ROWS (N_NODES * BATCH) /* 40000 */
#define SLOPE 0.2f

typedef __hip_bfloat16 bf16;
typedef short v8s __attribute__((ext_vector_type(8)));
typedef float v4f __attribute__((ext_vector_type(4)));

// ---- workspace layout (float/u32 slots) ----
// Ping-pong x (packed bf16 batch-pair) + ping-pong el/er; aggxb deleted.
#define WS_XA       0         /* 20000*64 u32 */
#define WS_XB       1280000   /* 20000*64 u32 */
#define WS_ELA      2560000   /* 160,000 */
#define WS_ERA      2720000   /* 160,000 */
#define WS_ELB      2880000   /* 160,000 */
#define WS_ERB      3040000   /* 160,000 */
#define WS_DEG      3200000   /* 20,032 ints */
#define WS_ROWSTART 3220032   /* 20,032 ints (20001 used) */
#define WS_CUR      3240064   /* 20,032 ints */
#define WS_CSRC     3260096   /* 320,000 ints */
#define WS_WGBPK    3580096   /* 16384 u16 */
#define WS_WRESBPK  3588288   /* 4096 u16 */
#define WS_WX8PK    3590336   /* 1024 u16 */
#define WS_WENCBPK  3590848   /* 2048 u16 */
#define WS_WDECBPK  3591872   /* 1024 u16 */
#define WS_BGM      3592384   /* 64 floats */
#define WS_END      3592448   /* ~14.4 MB */

__device__ __forceinline__ float us2f(unsigned short u) {
    union { unsigned int i; float f; } z; z.i = ((unsigned int)u) << 16; return z.f;
}
__device__ __forceinline__ unsigned short f2us(float f) {
    bf16 b = __float2bfloat16(f);
    return *(unsigned short*)&b;
}
__device__ __forceinline__ float ld(const void* p, int i, int isbf) {
    if (isbf) return us2f(((const unsigned short*)p)[i]);
    return ((const float*)p)[i];
}
__device__ __forceinline__ float lrexp(float v) {
    v = v > 0.f ? v : SLOPE * v;
    return __expf(fminf(v, 60.f));
}

// Inline bf16-vs-fp32 sniffer: 64 even 16-bit halves of h per wave.
__device__ __forceinline__ int sniff64(const void* h) {
    const unsigned short* u = (const unsigned short*)h;
    int lane = threadIdx.x & 63;
    unsigned short v = u[2 * lane];
    int ef = (v >> 7) & 0xFF;
    unsigned long long m = __ballot(ef >= 100 && ef <= 150);
    return __popcll(m) >= 48;
}

// Pack all B-operands into MFMA-fragment-native layout (one 16B load per frag).
// Blocks 18..37 additionally zero the deg array (replaces a hipMemsetAsync dispatch).
__global__ __launch_bounds__(256) void k_prep(const void* __restrict__ h,
                                              const void* __restrict__ Wg,
                                              const void* __restrict__ al,
                                              const void* __restrict__ ar,
                                              const void* __restrict__ Wr,
                                              const void* __restrict__ We,
                                              const void* __restrict__ Wd,
                                              const void* __restrict__ bg,
                                              unsigned short* __restrict__ WgBpk,
                                              unsigned short* __restrict__ WresBpk,
                                              unsigned short* __restrict__ Wx8pk,
                                              unsigned short* __restrict__ WencBpk,
                                              unsigned short* __restrict__ WdecBpk,
                                              float* __restrict__ bgm,
                                              int* __restrict__ deg) {
    int t = threadIdx.x, b = blockIdx.x;
    if (b >= 18) {
        int base = (b - 18) * 1024 + t * 4;
#pragma unroll
        for (int i = 0; i < 4; i++)
            if (base + i < 20032) deg[base + i] = 0;
        return;
    }
    const int isbf = sniff64(h);
    if (b < 16) {
#pragma unroll
        for (int q = 0; q < 4; q++) {
            int idx = b * 1024 + q * 256 + t;
            int j = idx & 7, m16 = (idx >> 3) & 15, quad = (idx >> 7) & 3;
            int ks = (idx >> 9) & 1, ct = (idx >> 10) & 3, hh = (idx >> 12) & 3;
            int k = ks * 32 + quad * 8 + j;
            int c = hh * 64 + ct * 16 + m16;
            WgBpk[idx] = f2us(ld(Wg, k * 256 + c, isbf));
        }
    } else if (b == 16) {
#pragma unroll
        for (int q = 0; q < 4; q++) {
            int idx = q * 256 + t;
            int j = idx & 7, m16 = (idx >> 3) & 15, quad = (idx >> 7) & 3;
            int ks = (idx >> 9) & 1;
            int k = ks * 32 + quad * 8 + j;
            float v = 0.f;
            if (m16 < 8) {
                int hh = m16 & 3, lr = m16 >> 2;
                const void* a = lr ? ar : al;
                for (int d = 0; d < 64; d++)
                    v += ld(Wg, k * 256 + hh * 64 + d, isbf) * ld(a, hh * 64 + d, isbf);
            }
            Wx8pk[idx] = f2us(v);
        }
#pragma unroll
        for (int q = 0; q < 8; q++) {
            int idx = q * 256 + t;
            int j = idx & 7, m16 = (idx >> 3) & 15, quad = (idx >> 7) & 3, ct = idx >> 9;
            int k = quad * 8 + j;
            WencBpk[idx] = f2us(ld(We, k * 64 + ct * 16 + m16, isbf));
        }
#pragma unroll
        for (int q = 0; q < 4; q++) {
            int idx = q * 256 + t;
            int j = idx & 7, m16 = (idx >> 3) & 15, quad = (idx >> 7) & 3;
            int ks = (idx >> 9) & 1;
            int k = ks * 32 + quad * 8 + j;
            WdecBpk[idx] = (m16 < 8) ? f2us(ld(Wd, k * 8 + m16, isbf)) : (unsigned short)0;
        }
        if (t < 64) {
            float s = 0.f;
            for (int hh = 0; hh < 4; hh++) s += ld(bg, hh * 64 + t, isbf);
            bgm[t] = 0.25f * s;
        }
    } else {
#pragma unroll
        for (int q = 0; q < 16; q++) {
            int idx = q * 256 + t;
            int j = idx & 7, m16 = (idx >> 3) & 15, quad = (idx >> 7) & 3;
            int ks = (idx >> 9) & 1;
            int k = ks * 32 + quad * 8 + j;
            WresBpk[idx] = f2us(ld(Wr, k * 64 + ((idx >> 10) & 3) * 16 + m16, isbf));
        }
    }
}

// ---- CSR build ----
__global__ __launch_bounds__(256) void k_hist(const int* __restrict__ dst, int* __restrict__ deg) {
    int e = blockIdx.x * 256 + threadIdx.x;
    if (e < N_EDGES) atomicAdd(&deg[dst[e]], 1);
}

__global__ __launch_bounds__(1024) void k_scan(const int* __restrict__ deg,
                                               int* __restrict__ rowstart,
                                               int* __restrict__ cursor) {
    __shared__ int ssum[1024];
    int t = threadIdx.x;
    int base = t * 20;
    int local[20];
    int s = 0;
#pragma unroll
    for (int i = 0; i < 20; i++) {
        int v = (base + i < N_NODES) ? deg[base + i] : 0;
        local[i] = s;
        s += v;
    }
    ssum[t] = s;
    __syncthreads();
    for (int off = 1; off < 1024; off <<= 1) {
        int v = (t >= off) ? ssum[t - off] : 0;
        __syncthreads();
        if (t >= off) ssum[t] += v;
        __syncthreads();
    }
    int prev = (t == 0) ? 0 : ssum[t - 1];
#pragma unroll
    for (int i = 0; i < 20; i++) {
        if (base + i < N_NODES) {
            int v = prev + local[i];
            rowstart[base + i] = v;
            cursor[base + i] = v;
        }
    }
    if (t == 1023) rowstart[N_NODES] = ssum[1023];
}

__global__ __launch_bounds__(256) void k_scatter(const int* __restrict__ src,
                                                 const int* __restrict__ dst,
                                                 int* __restrict__ cursor,
                                                 int* __restrict__ csrc) {
    int e = blockIdx.x * 256 + threadIdx.x;
    if (e >= N_EDGES) return;
    int pos = atomicAdd(&cursor[dst[e]], 1);
    csrc[pos] = src[e];
}

// Fused encoder: xb32 (packed bf16 batch-pair x) + el/er, via one K=32 MFMA step.
__global__ __launch_bounds__(256) void k_enc2(const void* __restrict__ h,
                                              const unsigned short* __restrict__ WencBpk,
                                              const void* __restrict__ benc,
                                              const unsigned short* __restrict__ Wx8pk,
                                              unsigned int* __restrict__ xb32,
                                              float* __restrict__ el,
                                              float* __restrict__ er) {
    const int isbf = sniff64(h);
    __shared__ unsigned short sXb[64 * 64];
    int t = threadIdx.x;
    int w = t >> 6, lane = t & 63, quad = lane >> 4, m16 = lane & 15;
    int row0 = blockIdx.x * 64;
    int grow = row0 + w * 16 + m16;
    int n = grow >> 1, b = grow & 1;

    v8s Af;
    size_t hb = (size_t)(b * N_NODES + n) * IN_DIM + quad * 8;
    if (isbf) {
        Af = *(const v8s*)((const unsigned short*)h + hb);
    } else {
        const float4* hp = (const float4*)((const float*)h + hb);
        float4 xa = hp[0], xbv = hp[1];
        Af[0] = (short)f2us(xa.x);  Af[1] = (short)f2us(xa.y);
        Af[2] = (short)f2us(xa.z);  Af[3] = (short)f2us(xa.w);
        Af[4] = (short)f2us(xbv.x); Af[5] = (short)f2us(xbv.y);
        Af[6] = (short)f2us(xbv.z); Af[7] = (short)f2us(xbv.w);
    }

    v4f acc[4];
#pragma unroll
    for (int ct = 0; ct < 4; ct++) {
        v8s Bf = *(const v8s*)(WencBpk + ((ct << 9) | (quad << 7) | (m16 << 3)));
        acc[ct] = __builtin_amdgcn_mfma_f32_16x16x32_bf16(Af, Bf, (v4f)(0.f), 0, 0, 0);
    }

#pragma unroll
    for (int ct = 0; ct < 4; ct++) {
        int col = ct * 16 + m16;
        float bv = ld(benc, col, isbf);
        float vr[4];
        int rloc0 = w * 16 + quad * 4;
#pragma unroll
        for (int r = 0; r < 4; r++) {
            vr[r] = acc[ct][r] + bv;
            sXb[(rloc0 + r) * 64 + col] = f2us(vr[r]);
        }
        int nd0 = (row0 + rloc0) >> 1;
        xb32[(size_t)nd0 * 64 + col] =
            (unsigned int)f2us(vr[0]) | ((unsigned int)f2us(vr[1]) << 16);
        xb32[(size_t)(nd0 + 1) * 64 + col] =
            (unsigned int)f2us(vr[2]) | ((unsigned int)f2us(vr[3]) << 16);
    }
    __syncthreads();
    v4f e8 = (v4f)(0.f);
#pragma unroll
    for (int ks = 0; ks < 2; ks++) {
        v8s Af2 = *(const v8s*)(sXb + (w * 16 + m16) * 64 + ks * 32 + quad * 8);
        v8s Bf = *(const v8s*)(Wx8pk + (((ks * 4 + quad) << 7) + (m16 << 3)));
        e8 = __builtin_amdgcn_mfma_f32_16x16x32_bf16(Af2, Bf, e8, 0, 0, 0);
    }
    if (m16 < 8) {
#pragma unroll
        for (int r = 0; r < 4; r++) {
            int gr = row0 + w * 16 + quad * 4 + r;
            float v = e8[r];
            if (m16 < 4) el[gr * 4 + m16] = v;
            else         er[gr * 4 + (m16 - 4)] = v;
        }
    }
}

// Fused round: agg (2 nodes per wave, K-split 16+16 slots) -> LDS handoff -> update.
// Block = 256 threads = 4 waves = 8 nodes = 16 rows.
// emit=1: write x_out + el_out/er_out (next round).  emit=0: fused decoder -> out.
__global__ __launch_bounds__(256) void k_round(const int* __restrict__ rowstart,
                                               const int* __restrict__ csrc,
                                               const float* __restrict__ el_in,
                                               const float* __restrict__ er_in,
                                               const unsigned int* __restrict__ x_in,
                                               const unsigned short* __restrict__ WgBpk,
                                               const unsigned short* __restrict__ WresBpk,
                                               const unsigned short* __restrict__ Wx8pk,
                                               const unsigned short* __restrict__ WdecBpk,
                                               const void* __restrict__ h,
                                               const void* __restrict__ br,
                                               const void* __restrict__ bd,
                                               const float* __restrict__ bgm,
                                               unsigned int* __restrict__ x_out,
                                               float* __restrict__ el_out,
                                               float* __restrict__ er_out,
                                               void* __restrict__ out,
                                               int emit) {
    const int isbf = sniff64(h);
    __shared__ unsigned short sAgg[4 * 16 * 64];  // [head][row16][col ^ swz(row)] bf16
    __shared__ unsigned short sXb[16 * 64];
    int t = threadIdx.x;
    int w = t >> 6, lane = t & 63, quad = lane >> 4, m16 = lane & 15;
    int i8 = m16 & 15 & 7;

    // ================= AGG phase: wave w owns nodes nA, nA+1 =================
    // A rows 0..7  = node A's (b,h) combos;  rows 8..15 = node B's.
    // K slots 0..15 (quads 0,1) = node A edges; slots 16..31 (quads 2,3) = node B edges.
    int nA = blockIdx.x * 8 + w * 2;
    int begA = rowstart[nA], endA = rowstart[nA + 1], endB = rowstart[nA + 2];
    int begB = endA;
    int rowNode = (m16 < 8) ? nA : (nA + 1);
    float erv = er_in[rowNode * 8 + i8];
    int beg = (quad < 2) ? begA : begB;
    int end = (quad < 2) ? endA : endB;
    int off = ((quad & 1) << 3);
    int active = ((m16 < 8) == (quad < 2));
    int itA = (endA - begA + 15) >> 4;
    int itB = (endB - begB + 15) >> 4;
    int itmax = itA > itB ? itA : itB;

    v4f accB0[4], accB1[4], accW;
#pragma unroll
    for (int tl = 0; tl < 4; tl++) { accB0[tl] = (v4f)(0.f); accB1[tl] = (v4f)(0.f); }
    accW = (v4f)(0.f);
    v8s Bones;
#pragma unroll
    for (int j = 0; j < 8; j++) Bones[j] = (short)0x3F80;  // bf16 1.0

    for (int it = 0; it < itmax; ++it) {
        int p0 = beg + it * 16 + off;
        int s[8];
#pragma unroll
        for (int j = 0; j < 8; j++) {
            int idx = p0 + j;
            s[j] = csrc[idx < end ? idx : 0];  // padded slots -> csrc[0] (weight forced 0)
        }
        v8s Af;
#pragma unroll
        for (int j = 0; j < 8; j++) {
            float wv = 0.f;
            if (active && (p0 + j < end))
                wv = lrexp(el_in[s[j] * 8 + i8] + erv);
            Af[j] = (short)f2us(wv);
        }
        accW = __builtin_amdgcn_mfma_f32_16x16x32_bf16(Af, Bones, accW, 0, 0, 0);
#pragma unroll
        for (int tl = 0; tl < 4; tl++) {
            v8s B0, B1;
#pragma unroll
            for (int j = 0; j < 8; j++) {
                unsigned int q = x_in[(size_t)s[j] * 64 + tl * 16 + m16];
                B0[j] = (short)(q & 0xffffu);
                B1[j] = (short)(q >> 16);
            }
            accB0[tl] = __builtin_amdgcn_mfma_f32_16x16x32_bf16(Af, B0, accB0[tl], 0, 0, 0);
            accB1[tl] = __builtin_amdgcn_mfma_f32_16x16x32_bf16(Af, B1, accB1[tl], 0, 0, 0);
        }
    }

    // C row rr = quad*4+r: node = quad>>1, batch = quad&1, head = r.
    // Storage row16 = w*4 + quad (== grow - blockIdx*16). XOR-swizzle cols (G4).
    {
        int row16 = w * 4 + quad;
        int swz = (row16 & 7) << 3;
#pragma unroll
        for (int tl = 0; tl < 4; tl++) {
#pragma unroll
            for (int r = 0; r < 4; r++) {
                float wss = accW[r];
                float mine = (quad & 1) ? accB1[tl][r] : accB0[tl][r];
                float v = (wss > 0.f) ? mine / (4.f * wss) : 0.f;
                int col = tl * 16 + m16;
                sAgg[((r * 16 + row16) << 6) | (col ^ swz)] = f2us(v);
            }
        }
    }
    __syncthreads();

    // ================= UPDATE phase: all 4 waves share the 16 rows; wave = col-tile ct =================
    int grow0 = blockIdx.x * 16;
    int grow = grow0 + m16;
    int nd = grow >> 1;
    unsigned sh = (grow & 1) * 16;
    int ct = w;

    v4f acc = (v4f)(0.f);
#pragma unroll
    for (int hh = 0; hh < 4; hh++) {
#pragma unroll
        for (int ks = 0; ks < 2; ks++) {
            int si = ((hh * 16 + m16) << 6) | ((ks * 32 + quad * 8) ^ ((m16 & 7) << 3));
            v8s Af = *(const v8s*)(sAgg + si);
            v8s Bf = *(const v8s*)(WgBpk + ((hh << 12) | (ct << 10) | (ks << 9) | (quad << 7) | (m16 << 3)));
            acc = __builtin_amdgcn_mfma_f32_16x16x32_bf16(Af, Bf, acc, 0, 0, 0);
        }
    }
#pragma unroll
    for (int ks = 0; ks < 2; ks++) {
        const uint4* xp = (const uint4*)(x_in + (size_t)nd * 64 + ks * 32 + quad * 8);
        uint4 qa = xp[0], qb = xp[1];
        v8s Af;
        Af[0] = (short)((qa.x >> sh) & 0xffffu);
        Af[1] = (short)((qa.y >> sh) & 0xffffu);
        Af[2] = (short)((qa.z >> sh) & 0xffffu);
        Af[3] = (short)((qa.w >> sh) & 0xffffu);
        Af[4] = (short)((qb.x >> sh) & 0xffffu);
        Af[5] = (short)((qb.y >> sh) & 0xffffu);
        Af[6] = (short)((qb.z >> sh) & 0xffffu);
        Af[7] = (short)((qb.w >> sh) & 0xffffu);
        v8s Bf = *(const v8s*)(WresBpk + ((ct << 10) | (ks << 9) | (quad << 7) | (m16 << 3)));
        acc = __builtin_amdgcn_mfma_f32_16x16x32_bf16(Af, Bf, acc, 0, 0, 0);
    }

    {
        int col = ct * 16 + m16;
        float bv = ld(br, col, isbf) + bgm[col];
        float vr[4];
#pragma unroll
        for (int r = 0; r < 4; r++) {
            float v = acc[r] + bv;
            v = v > 0.f ? v : expm1f(v);
            vr[r] = v;
            sXb[(quad * 4 + r) * 64 + col] = f2us(v);
        }
        if (emit) {
            int nd0 = (grow0 + quad * 4) >> 1;
            x_out[(size_t)nd0 * 64 + col] =
                (unsigned int)f2us(vr[0]) | ((unsigned int)f2us(vr[1]) << 16);
            x_out[(size_t)(nd0 + 1) * 64 + col] =
                (unsigned int)f2us(vr[2]) | ((unsigned int)f2us(vr[3]) << 16);
        }
    }
    __syncthreads();

    if (w == 0) {
        if (emit) {
            v4f e8 = (v4f)(0.f);
#pragma unroll
            for (int ks = 0; ks < 2; ks++) {
                v8s Af = *(const v8s*)(sXb + m16 * 64 + ks * 32 + quad * 8);
                v8s Bf = *(const v8s*)(Wx8pk + (((ks * 4 + quad) << 7) + (m16 << 3)));
                e8 = __builtin_amdgcn_mfma_f32_16x16x32_bf16(Af, Bf, e8, 0, 0, 0);
            }
            if (m16 < 8) {
#pragma unroll
                for (int r = 0; r < 4; r++) {
                    int gr = grow0 + quad * 4 + r;
                    float v = e8[r];
                    if (m16 < 4) el_out[gr * 4 + m16] = v;
                    else         er_out[gr * 4 + (m16 - 4)] = v;
                }
            }
        } else {
            v4f o8 = (v4f)(0.f);
#pragma unroll
            for (int ks = 0; ks < 2; ks++) {
                v8s Af = *(const v8s*)(sXb + m16 * 64 + ks * 32 + quad * 8);
                v8s Bf = *(const v8s*)(WdecBpk + ((ks << 9) | (quad << 7) | (m16 << 3)));
                o8 = __builtin_amdgcn_mfma_f32_16x16x32_bf16(Af, Bf, o8, 0, 0, 0);
            }
            if (m16 < 8) {
                float bvd = ld(bd, m16, isbf);
#pragma unroll
                for (int r = 0; r < 4; r++) {
                    int gr = grow0 + quad * 4 + r;
                    int nn = gr >> 1, bb = gr & 1;
                    size_t oi = (size_t)(bb * N_NODES + nn) * OUT_DIM + m16;
                    float v = o8[r] + bvd;
                    if (isbf) ((unsigned short*)out)[oi] = f2us(v);
                    else      ((float*)out)[oi] = v;
                }
            }
        }
    }
}

extern "C" void kernel_launch(void* const* d_in, const int* in_sizes, int n_in,
                              void* d_out, int out_size, void* d_ws, size_t ws_size,
                              hipStream_t stream) {
    const void* h     = d_in[0];
    const int*  ei    = (const int*)d_in[1];
    const void* W_enc = d_in[2];
    const void* b_enc = d_in[3];
    const void* W_gat = d_in[4];
    const void* a_l   = d_in[5];
    const void* a_r   = d_in[6];
    const void* b_gat = d_in[7];
    const void* W_res = d_in[8];
    const void* b_res = d_in[9];
    const void* W_dec = d_in[10];
    const void* b_dec = d_in[11];

    float* ws = (float*)d_ws;
    unsigned int* xA = (unsigned int*)(ws + WS_XA);
    unsigned int* xB = (unsigned int*)(ws + WS_XB);
    float* elA      = ws + WS_ELA;
    float* erA      = ws + WS_ERA;
    float* elB      = ws + WS_ELB;
    float* erB      = ws + WS_ERB;
    int*   deg      = (int*)(ws + WS_DEG);
    int*   rowstart = (int*)(ws + WS_ROWSTART);
    int*   cursor   = (int*)(ws + WS_CUR);
    int*   csrc     = (int*)(ws + WS_CSRC);
    unsigned short* WgBpk   = (unsigned short*)(ws + WS_WGBPK);
    unsigned short* WresBpk = (unsigned short*)(ws + WS_WRESBPK);
    unsigned short* Wx8pk   = (unsigned short*)(ws + WS_WX8PK);
    unsigned short* WencBpk = (unsigned short*)(ws + WS_WENCBPK);
    unsigned short* WdecBpk = (unsigned short*)(ws + WS_WDECBPK);
    float* bgm      = ws + WS_BGM;

    const int* src = ei;
    const int* dst = ei + N_EDGES;

    k_prep<<<38, 256, 0, stream>>>(h, W_gat, a_l, a_r, W_res, W_enc, W_dec, b_gat,
                                   WgBpk, WresBpk, Wx8pk, WencBpk, WdecBpk, bgm, deg);
    k_hist<<<(N_EDGES + 255) / 256, 256, 0, stream>>>(dst, deg);
    k_scan<<<1, 1024, 0, stream>>>(deg, rowstart, cursor);
    k_scatter<<<(N_EDGES + 255) / 256, 256, 0, stream>>>(src, dst, cursor, csrc);

    k_enc2<<<ROWS / 64, 256, 0, stream>>>(h, WencBpk, b_enc, Wx8pk, xA, elA, erA);

    // Round 1: read A buffers, write B buffers.
    k_round<<<N_NODES / 8, 256, 0, stream>>>(rowstart, csrc, elA, erA, xA,
                                             WgBpk, WresBpk, Wx8pk, WdecBpk,
                                             h, b_res, b_dec, bgm,
                                             xB, elB, erB, d_out, 1);
    // Round 2: read B buffers, fused decoder -> out.
    k_round<<<N_NODES / 8, 256, 0, stream>>>(rowstart, csrc, elB, erB, xB,
                                             WgBpk, WresBpk, Wx8pk, WdecBpk,
                                             h, b_res, b_dec, bgm,
                                             xA, elA, erA, d_out, 0);
}